// Round 5
// baseline (75419.586 us; speedup 1.0000x reference)
//
#include <hip/hip_runtime.h>
#include <math.h>

// BatchFrechetMean: inductive geodesic mean of 256 SPD 256x256 matrices.
// Eigh-free: fixed-interval Chebyshev polynomial evaluation of M^{-1/2} and S^t,
// persistent SINGLE-XCD kernel + agent-scope barrier, L2-local data plane.
//
// R8c: hang-hardened R8. R4(round) failure was opaque (trio exception, no
// pytest output). Only credible kernel-side hang: if XCC_ID misbehaves,
// participants scatter across XCDs while barrier counters were sc0-only
// (XCD-local) -> different L2 copies -> spin forever. Fixes:
//  1. ALL control-plane atomics (election/slot/barrier) via __hip_atomic_*
//     AGENT scope (coherent encodings; worked in R6/R7 from any XCD). A
//     broken placement now yields wrong data (visible test fail), not a hang.
//  2. Home XCD is CAS-elected by the first block (no hard-coded "XCD 0").
// Data plane unchanged: sc0 loads/stores served by home-XCD L2 (~200cy,
// 4.6 TB/s), NO fences/wbl2/inv in the k-loop.
//
// Theory (R8): R7 showed sc0+sc1 (MALL) data plane costs 13.3us/round (every
// operand load ~600-900cy). Single-XCD residency keeps the 5 MB working set
// in the home XCD's 4 MB L2; per-round L2 reads ~11.5 MB @4.6 TB/s ~ 2.5us +
// ~1-2us barrier -> ~4us/round -> 12-20 ms total.
//
// Spectral bounds (provable): lambda(f) in [1, ~5.2] => lambda(M) in [1, 5.5],
// lambda(S) in [1/5.75, 5.75]. Approximation intervals with margin:
//   x^{-1/2} on [0.95, 5.75], deg 11 (s=4, m=2)  -> err ~3e-5
//   x^{t}    on [0.17, 5.90], deg 39 (s=8, m=4)  -> err ~1e-6
//
// Perf history: R2 130ms -> R3 60ms -> R4 256blk 96ms -> R5 64blk 41.1ms ->
// R6 16blk agent-fence 102.5ms (wbl2/inv HBM round-trip/round) -> R7 MALL
// data plane 51ms (every load = MALL latency) -> R8c this (predict 12-20ms).

#define NPART 32
#define AM 0.95f
#define BM 5.75f
#define AS_ 0.17f
#define BS_ 5.90f

typedef __attribute__((ext_vector_type(8))) short bf16x8;
typedef __attribute__((ext_vector_type(4))) float f32x4;

enum {
  iXM = 0, iU2, iU4, iCBA, iCBB, iISQ, iSQ, iG,
  iXS, iV2, iV3, iV4, iV8, iSBA, iSBB, iSBC, iPP, iHH, iFK, NBUF
};

// Matrices stored as bf16 hi+lo planes (value = hi + lo, ~2^-16 rel err).
// ALL accesses use sc0 (bypass L1, coherent within the home XCD's L2).
__device__ __align__(16) short gHi[NBUF][65536];
__device__ __align__(16) short gLo[NBUF][65536];
__device__ float g_aS[256][40];   // per-step regrouped Cheb coeffs of x^{t_k}
__device__ float g_aM[12];        // regrouped Cheb coeffs of x^{-1/2}

struct __align__(128) Ctr { int v; int pad[31]; };  // one 128B line per counter
__device__ Ctr g_c1;              // barrier arrival counter (monotonic)
__device__ Ctr g_genc;            // published generation
__device__ Ctr g_slot;            // participant slot allocator
__device__ int g_xcd;             // CAS-elected home XCD (-1 = unset)

__device__ __forceinline__ short f2bf(float x) {
  unsigned u = __builtin_bit_cast(unsigned, x);
  unsigned r = (u + 0x7FFFu + ((u >> 16) & 1u)) >> 16;   // RNE to bf16
  return (short)(unsigned short)r;
}
__device__ __forceinline__ float bf2f(short h) {
  unsigned u = ((unsigned)(unsigned short)h) << 16;
  return __builtin_bit_cast(float, u);
}

// ---- L2-local data primitives (sc0 = bypass L1; home-XCD L2 = coherence pt) ----
__device__ __forceinline__ bf16x8 ldg_l2v(const short* p) {
  bf16x8 r;
  asm volatile("global_load_dwordx4 %0, %1, off sc0" : "=v"(r) : "v"(p));
  return r;  // caller must s_waitcnt vmcnt before use
}
__device__ __forceinline__ void stg_l2s(short* p, short v) {
  unsigned w = (unsigned)(unsigned short)v;
  asm volatile("global_store_short %0, %1, off sc0" :: "v"(p), "v"(w));
}
__device__ __forceinline__ void wrm(int m, int idx, float v) {
  short h = f2bf(v);
  stg_l2s(&gHi[m][idx], h);
  stg_l2s(&gLo[m][idx], f2bf(v - bf2f(h)));
}

// C(arow, bcol) fragment of A*B; B symmetric -> read B by rows (dwordx4).
// Split hi/lo bf16: 3 MFMAs per K-chunk, ~1e-5 rel err per matmul.
__device__ __forceinline__ f32x4 mmbf(int Ai, int Bi, int arow, int bcol, int kq) {
  const short* ah = gHi[Ai] + arow * 256 + kq;
  const short* al = gLo[Ai] + arow * 256 + kq;
  const short* bh = gHi[Bi] + bcol * 256 + kq;
  const short* bl = gLo[Bi] + bcol * 256 + kq;
  bf16x8 Ah[8], Al[8], Bh[8], Bl[8];
#pragma unroll
  for (int c = 0; c < 8; c++) {
    Ah[c] = ldg_l2v(ah + c * 32);
    Bh[c] = ldg_l2v(bh + c * 32);
    Al[c] = ldg_l2v(al + c * 32);
    Bl[c] = ldg_l2v(bl + c * 32);
  }
  asm volatile("s_waitcnt vmcnt(0)" ::: "memory");
  __builtin_amdgcn_sched_barrier(0);   // rule #18: no MFMA hoist above waitcnt
  f32x4 acc = {0.0f, 0.0f, 0.0f, 0.0f};
#pragma unroll
  for (int c = 0; c < 8; c++) {
    acc = __builtin_amdgcn_mfma_f32_16x16x32_bf16(Ah[c], Bh[c], acc, 0, 0, 0);
    acc = __builtin_amdgcn_mfma_f32_16x16x32_bf16(Al[c], Bh[c], acc, 0, 0, 0);
    acc = __builtin_amdgcn_mfma_f32_16x16x32_bf16(Ah[c], Bl[c], acc, 0, 0, 0);
  }
  return acc;
}

// Grid barrier. Release = every wave drains its own sc0 stores (vmcnt 0)
// before the block s_barrier -> data resident in home-XCD L2 before thread0's
// arrival RMW. Counters are AGENT-scope (coherent from ANY XCD -> no hang
// even if placement assumptions break). Acquire for data = nothing: sc0 loads
// can't hit stale L1, and producer+consumer share the home L2.
__device__ __forceinline__ void gridbar(int* sgen) {
  asm volatile("s_waitcnt vmcnt(0) lgkmcnt(0)" ::: "memory");
  __syncthreads();
  if (threadIdx.x == 0) {
    int n = *sgen;
    int v = __hip_atomic_fetch_add(&g_c1.v, 1, __ATOMIC_RELAXED,
                                   __HIP_MEMORY_SCOPE_AGENT);
    if (v == NPART * n + (NPART - 1))
      __hip_atomic_store(&g_genc.v, n + 1, __ATOMIC_RELAXED,
                         __HIP_MEMORY_SCOPE_AGENT);
    while (__hip_atomic_load(&g_genc.v, __ATOMIC_RELAXED,
                             __HIP_MEMORY_SCOPE_AGENT) <= n)
      __builtin_amdgcn_s_sleep(1);
    *sgen = n + 1;
  }
  __syncthreads();
  asm volatile("" ::: "memory");
}

// Chebyshev-PS regrouping: p = sum_j c_j T_j  ->  sum_i q_i(x) T_i(T_s(x)),
// q_i = sum_r a[i][r] T_r.  a[i][r] = 2c[is+r] - a[i+1][s-r] (a[i][0]=c[is]);
// a[0][r] = c[r] - 0.5 a[1][s-r]; a[0][0] = c[0].
__device__ void regroup_d(const double* c, float* outp, int s, int m) {
  double al[64];
  for (int i = m; i >= 1; i--)
    for (int r = 0; r < s; r++) {
      double v;
      if (r == 0) v = c[s * i];
      else v = 2.0 * c[s * i + r] - ((i == m) ? 0.0 : al[s * (i + 1) + (s - r)]);
      al[s * i + r] = v;
    }
  al[0] = c[0];
  for (int r = 1; r < s; r++) al[r] = c[r] - 0.5 * al[s + (s - r)];
  int tot = s * (m + 1);
  for (int j = 0; j < tot; j++) outp[j] = (float)al[j];
}

// Setup: per-step Chebyshev coefficients (128-node DCT in fp64) + state reset.
// Cross-kernel visibility via dispatch-boundary release/acquire (runtime).
__global__ void setup_kernel(const float* __restrict__ wts) {
  const int k = blockIdx.x;
  const int lane = threadIdx.x;
  __shared__ double s_fv[128];
  __shared__ double s_c[64];
  const double PI = 3.14159265358979323846;
  if (k < 256) {
    double w0 = (double)wts[2 * k], w1 = (double)wts[2 * k + 1];
    double t = 1.0 / (1.0 + exp(w0 - w1));     // softmax(...)[:,1]
    double c0 = 0.5 * ((double)AS_ + (double)BS_), h0 = 0.5 * ((double)BS_ - (double)AS_);
    for (int i = lane; i < 128; i += 64) {
      double th = (i + 0.5) * PI / 128.0;
      double y = c0 + h0 * cos(th);
      s_fv[i] = pow(y, t);
    }
    __syncthreads();
    if (lane < 40) {
      double s = 0.0;
      for (int i = 0; i < 128; i++) {
        double th = (i + 0.5) * PI / 128.0;
        s += s_fv[i] * cos((double)lane * th);
      }
      s_c[lane] = s * ((lane == 0) ? 1.0 : 2.0) / 128.0;
    }
    __syncthreads();
    if (lane == 0) regroup_d(s_c, g_aS[k], 8, 4);
  } else {
    double c0 = 0.5 * ((double)AM + (double)BM), h0 = 0.5 * ((double)BM - (double)AM);
    for (int i = lane; i < 128; i += 64) {
      double th = (i + 0.5) * PI / 128.0;
      double y = c0 + h0 * cos(th);
      s_fv[i] = 1.0 / sqrt(y);
    }
    __syncthreads();
    if (lane < 12) {
      double s = 0.0;
      for (int i = 0; i < 128; i++) {
        double th = (i + 0.5) * PI / 128.0;
        s += s_fv[i] * cos((double)lane * th);
      }
      s_c[lane] = s * ((lane == 0) ? 1.0 : 2.0) / 128.0;
    }
    __syncthreads();
    if (lane == 0) {
      regroup_d(s_c, g_aM, 4, 2);
      g_c1.v = 0; g_genc.v = 0; g_slot.v = 0; g_xcd = -1;
    }
  }
}

// 32 participants x 512 thr: 1 block/CU (8 waves, VGPR<=256), 2 waves/SIMD.
// 256 waves = one 16x16 C-tile per wave (R5 structure preserved).
__global__ void __launch_bounds__(512, 2) frechet_kernel(const float* __restrict__ f,
                                                         float* __restrict__ out) {
  __shared__ int s_vbid;
  __shared__ int s_gen;
  int xcc;
  asm volatile("s_getreg_b32 %0, hwreg(HW_REG_XCC_ID)" : "=s"(xcc));
  xcc &= 7;
  if (threadIdx.x == 0) {
    // Elect the home XCD: first block's XCC wins (no hard-coded ID).
    int expected = -1;
    bool won = __hip_atomic_compare_exchange_strong(
        &g_xcd, &expected, xcc, __ATOMIC_RELAXED, __ATOMIC_RELAXED,
        __HIP_MEMORY_SCOPE_AGENT);
    int chosen = won ? xcc : expected;
    int slot = -1;
    if (chosen == xcc)
      slot = __hip_atomic_fetch_add(&g_slot.v, 1, __ATOMIC_RELAXED,
                                    __HIP_MEMORY_SCOPE_AGENT);
    s_vbid = slot;
    s_gen = 0;
  }
  __syncthreads();
  const int vbid = s_vbid;
  if (vbid < 0 || vbid >= NPART) return;   // off-home or overflow: exit

  const int tid = threadIdx.x;
  const int lane = tid & 63, wave = tid >> 6;
  const int tr = (vbid >> 2) * 32, tc = (vbid & 3) * 64;  // 8x4 grid of 32x64
  const int sr = (wave >> 2) * 16, sc = (wave & 3) * 16;  // 2x4 waves of 16x16
  const int arow = tr + sr + (lane & 15);     // A-fragment row (global)
  const int colg = tc + sc + (lane & 15);     // C col = B-sym row (global)
  const int kq = (lane >> 4) * 8;             // K sub-offset within chunk
  const int row0 = tr + sr + (lane >> 4) * 4; // C rows for acc[0..3]
  const int fbase = (vbid * 512 + tid) * 4;   // 4 contiguous f elems / thread

  const float sM = 2.0f / (BM - AM), cM = 0.5f * (AM + BM);
  const float sS = 2.0f / (BS_ - AS_), cS = 0.5f * (AS_ + BS_);

  // Register-carried per-thread values (each at idx=(row0+r)*256+colg; every
  // scalar operand below was produced by THIS thread in an earlier round).
  float xmr[4], u2r[4], cbar[4], qm1r[4], qm0r[4], isqr[4];
  float xsr[4], v2r[4], v3r[4], v4r[4];
  float qs3r[4], qs2r[4], qs1r[4], qs0r[4], sbar[4], sbbr[4], sbcr[4];

  // Init: XM = sM*(I - cM*I) at tile positions; stage f_0 into bf16 planes.
  {
    float4 f0 = *(const float4*)(f + fbase);
    float fv[4] = {f0.x, f0.y, f0.z, f0.w};
#pragma unroll
    for (int r = 0; r < 4; r++) {
      int row = row0 + r, idx = row * 256 + colg;
      xmr[r] = (row == colg) ? sM * (1.0f - cM) : 0.0f;
      wrm(iXM, idx, xmr[r]);
      wrm(iFK, fbase + r, fv[r]);
    }
  }
  gridbar(&s_gen);

  for (int k = 0; k < 256; k++) {
    const float* aS = g_aS[k];
    const float* aM = g_aM;

    // ---- ISQ = p(M) ~ M^{-1/2}: s=4, m=2, deg 11 ----
    { // r1: U2 = 2*XM*XM - I
      f32x4 a = mmbf(iXM, iXM, arow, colg, kq);
#pragma unroll
      for (int r = 0; r < 4; r++) {
        int row = row0 + r, idx = row * 256 + colg;
        u2r[r] = 2.0f * a[r] - ((row == colg) ? 1.0f : 0.0f);
        wrm(iU2, idx, u2r[r]);
      }
    }
    gridbar(&s_gen);
    { // r2: U3 (regs), U4 ; q2 (CBA) global, Q1/Q0 combos register-only
      f32x4 a3 = mmbf(iXM, iU2, arow, colg, kq);
      f32x4 a4 = mmbf(iU2, iU2, arow, colg, kq);
#pragma unroll
      for (int r = 0; r < 4; r++) {
        int row = row0 + r, idx = row * 256 + colg;
        float dI = (row == colg) ? 1.0f : 0.0f;
        float xm = xmr[r], u2 = u2r[r];
        float u3 = 2.0f * a3[r] - xm;
        wrm(iU4, idx, 2.0f * a4[r] - dI);
        cbar[r] = aM[8] * dI + aM[9] * xm + aM[10] * u2 + aM[11] * u3;
        wrm(iCBA, idx, cbar[r]);
        qm1r[r] = aM[4] * dI + aM[5] * xm + aM[6] * u2 + aM[7] * u3;
        qm0r[r] = aM[0] * dI + aM[1] * xm + aM[2] * u2 + aM[3] * u3;
      }
    }
    gridbar(&s_gen);
    { // r3: CBB = 2*U4*CBA + Q1
      f32x4 a = mmbf(iU4, iCBA, arow, colg, kq);
#pragma unroll
      for (int r = 0; r < 4; r++) {
        int idx = (row0 + r) * 256 + colg;
        wrm(iCBB, idx, 2.0f * a[r] + qm1r[r]);
      }
    }
    gridbar(&s_gen);
    { // r4: ISQ = U4*CBB - CBA + Q0
      f32x4 a = mmbf(iU4, iCBB, arow, colg, kq);
#pragma unroll
      for (int r = 0; r < 4; r++) {
        int idx = (row0 + r) * 256 + colg;
        isqr[r] = a[r] - cbar[r] + qm0r[r];
        wrm(iISQ, idx, isqr[r]);
      }
    }
    gridbar(&s_gen);
    { // r5: SQ = (1/sM)*XM*ISQ + cM*ISQ ; G = ISQ*FK
      f32x4 a = mmbf(iXM, iISQ, arow, colg, kq);
      f32x4 b = mmbf(iISQ, iFK, arow, colg, kq);
#pragma unroll
      for (int r = 0; r < 4; r++) {
        int idx = (row0 + r) * 256 + colg;
        wrm(iSQ, idx, a[r] * (1.0f / sM) + cM * isqr[r]);
        wrm(iG, idx, b[r]);
      }
    }
    gridbar(&s_gen);
    { // r6: XS = sS*(G*ISQ) - sS*cS*I
      f32x4 a = mmbf(iG, iISQ, arow, colg, kq);
#pragma unroll
      for (int r = 0; r < 4; r++) {
        int row = row0 + r, idx = row * 256 + colg;
        xsr[r] = sS * a[r] - sS * cS * ((row == colg) ? 1.0f : 0.0f);
        wrm(iXS, idx, xsr[r]);
      }
    }
    gridbar(&s_gen);

    // ---- P = p(S) ~ S^t: s=8, m=4, deg 39 ----
    { // r7: V2 = 2*XS*XS - I
      f32x4 a = mmbf(iXS, iXS, arow, colg, kq);
#pragma unroll
      for (int r = 0; r < 4; r++) {
        int row = row0 + r, idx = row * 256 + colg;
        v2r[r] = 2.0f * a[r] - ((row == colg) ? 1.0f : 0.0f);
        wrm(iV2, idx, v2r[r]);
      }
    }
    gridbar(&s_gen);
    { // r8: V3 = 2*XS*V2 - XS ; V4 = 2*V2*V2 - I
      f32x4 a = mmbf(iXS, iV2, arow, colg, kq);
      f32x4 b = mmbf(iV2, iV2, arow, colg, kq);
#pragma unroll
      for (int r = 0; r < 4; r++) {
        int row = row0 + r, idx = row * 256 + colg;
        float dI = (row == colg) ? 1.0f : 0.0f;
        v3r[r] = 2.0f * a[r] - xsr[r];
        v4r[r] = 2.0f * b[r] - dI;
        wrm(iV3, idx, v3r[r]);
        wrm(iV4, idx, v4r[r]);
      }
    }
    gridbar(&s_gen);
    { // r9: V5..V7 (regs), V8, q4 (SBA) global; Q3..Q0 register-only; f_{k+1}
      f32x4 fq;
      if (k < 255) {
        const f32x4* fp = (const f32x4*)(f + (size_t)(k + 1) * 65536 + fbase);
        fq = __builtin_nontemporal_load(fp);   // don't pollute home-XCD L2
      } else {
        fq = (f32x4){0.f, 0.f, 0.f, 0.f};
      }
      f32x4 a5 = mmbf(iV2, iV3, arow, colg, kq);
      f32x4 a6 = mmbf(iV3, iV3, arow, colg, kq);
      f32x4 a7 = mmbf(iV3, iV4, arow, colg, kq);
      f32x4 a8 = mmbf(iV4, iV4, arow, colg, kq);
#pragma unroll
      for (int r = 0; r < 4; r++) {
        int row = row0 + r, idx = row * 256 + colg;
        float dI = (row == colg) ? 1.0f : 0.0f;
        float xs = xsr[r], v2 = v2r[r], v3 = v3r[r], v4 = v4r[r];
        float v5 = 2.0f * a5[r] - xs;   // T5 = 2*T2*T3 - T1
        float v6 = 2.0f * a6[r] - dI;   // T6 = 2*T3*T3 - T0
        float v7 = 2.0f * a7[r] - xs;   // T7 = 2*T3*T4 - T1
        float v8 = 2.0f * a8[r] - dI;   // T8 = 2*T4*T4 - T0
        wrm(iV8, idx, v8);
        sbar[r] = aS[32] * dI + aS[33] * xs + aS[34] * v2 + aS[35] * v3 +
                  aS[36] * v4 + aS[37] * v5 + aS[38] * v6 + aS[39] * v7;
        wrm(iSBA, idx, sbar[r]);
        qs3r[r] = aS[24] * dI + aS[25] * xs + aS[26] * v2 + aS[27] * v3 +
                  aS[28] * v4 + aS[29] * v5 + aS[30] * v6 + aS[31] * v7;
        qs2r[r] = aS[16] * dI + aS[17] * xs + aS[18] * v2 + aS[19] * v3 +
                  aS[20] * v4 + aS[21] * v5 + aS[22] * v6 + aS[23] * v7;
        qs1r[r] = aS[8] * dI + aS[9] * xs + aS[10] * v2 + aS[11] * v3 +
                  aS[12] * v4 + aS[13] * v5 + aS[14] * v6 + aS[15] * v7;
        qs0r[r] = aS[0] * dI + aS[1] * xs + aS[2] * v2 + aS[3] * v3 +
                  aS[4] * v4 + aS[5] * v5 + aS[6] * v6 + aS[7] * v7;
      }
      if (k < 255) {
        float fv[4] = {fq[0], fq[1], fq[2], fq[3]};
#pragma unroll
        for (int r = 0; r < 4; r++) wrm(iFK, fbase + r, fv[r]);
      }
    }
    gridbar(&s_gen);
    { // r10: b3 = 2*V8*b4 + Q3
      f32x4 a = mmbf(iV8, iSBA, arow, colg, kq);
#pragma unroll
      for (int r = 0; r < 4; r++) {
        int idx = (row0 + r) * 256 + colg;
        sbbr[r] = 2.0f * a[r] + qs3r[r];
        wrm(iSBB, idx, sbbr[r]);
      }
    }
    gridbar(&s_gen);
    { // r11: b2 = 2*V8*b3 - b4 + Q2
      f32x4 a = mmbf(iV8, iSBB, arow, colg, kq);
#pragma unroll
      for (int r = 0; r < 4; r++) {
        int idx = (row0 + r) * 256 + colg;
        sbcr[r] = 2.0f * a[r] - sbar[r] + qs2r[r];
        wrm(iSBC, idx, sbcr[r]);
      }
    }
    gridbar(&s_gen);
    { // r12: b1 = 2*V8*b2 - b3 + Q1  (reuses SBA slot)
      f32x4 a = mmbf(iV8, iSBC, arow, colg, kq);
#pragma unroll
      for (int r = 0; r < 4; r++) {
        int idx = (row0 + r) * 256 + colg;
        wrm(iSBA, idx, 2.0f * a[r] - sbbr[r] + qs1r[r]);
      }
    }
    gridbar(&s_gen);
    { // r13: P = V8*b1 - b2 + Q0
      f32x4 a = mmbf(iV8, iSBA, arow, colg, kq);
#pragma unroll
      for (int r = 0; r < 4; r++) {
        int idx = (row0 + r) * 256 + colg;
        wrm(iPP, idx, a[r] - sbcr[r] + qs0r[r]);
      }
    }
    gridbar(&s_gen);
    { // r14: HH = SQ*P
      f32x4 a = mmbf(iSQ, iPP, arow, colg, kq);
#pragma unroll
      for (int r = 0; r < 4; r++) {
        int idx = (row0 + r) * 256 + colg;
        wrm(iHH, idx, a[r]);
      }
    }
    gridbar(&s_gen);
    { // r15: Mn = HH*SQ -> out[k] (fp32, NT); XM_next = sM*(Mn - cM*I)
      f32x4 a = mmbf(iHH, iSQ, arow, colg, kq);
      float* ok = out + (size_t)k * 65536;
#pragma unroll
      for (int r = 0; r < 4; r++) {
        int row = row0 + r, idx = row * 256 + colg;
        float dI = (row == colg) ? 1.0f : 0.0f;
        float v = a[r];
        __builtin_nontemporal_store(v, ok + idx);
        xmr[r] = sM * (v - cM * dI);
        wrm(iXM, idx, xmr[r]);
      }
    }
    gridbar(&s_gen);
  }
}

extern "C" void kernel_launch(void* const* d_in, const int* in_sizes, int n_in,
                              void* d_out, int out_size, void* d_ws, size_t ws_size,
                              hipStream_t stream) {
  (void)in_sizes; (void)n_in; (void)d_ws; (void)ws_size; (void)out_size;
  const float* f = (const float*)d_in[0];
  const float* w = (const float*)d_in[1];
  float* out = (float*)d_out;

  setup_kernel<<<dim3(257), dim3(64), 0, stream>>>(w);

  // 1024 probe blocks; the first block CAS-elects its XCD as "home"; the
  // first NPART=32 blocks landing on the home XCD participate (occupying its
  // 32 CUs); all others exit instantly. CP always makes progress: either the
  // home XCD has free CUs, or all 32 participants are resident and the
  // (agent-scope, placement-independent) barrier is satisfiable.
  frechet_kernel<<<dim3(1024), dim3(512), 0, stream>>>(f, out);
}

// Round 6
// 44936.020 us; speedup vs baseline: 1.6784x; 1.6784x over previous
//
#include <hip/hip_runtime.h>
#include <math.h>

// BatchFrechetMean: inductive geodesic mean of 256 SPD 256x256 matrices.
// Eigh-free Chebyshev evaluation of M^{-1/2} and S^t, persistent SINGLE-XCD
// kernel, PLAIN-CACHED data plane + L1-only invalidation barrier.
//
// R9. Evidence so far: R5 (plain + agent wbl2/inv fences) = 10.7us/round,
// dirty set through HBM each round. R7 (sc0+sc1) and R8c (sc0 only) both show
// FETCH ~= full operand stream (11.3/12.6 GB) => on gfx950, ANY sc-bit data
// access bypasses L2 allocation; every load pays MALL latency. Fix: data plane
// uses PLAIN loads/stores (L1+L2 cached, compiler-scheduled). Coherence comes
// from structure: all 32 participants on ONE XCD share its L2 (L1 is
// write-through on CDNA), so the only stale state is per-CU L1 -> barrier does
// vmcnt-drain + MALL-scope arrival atomics + bare `buffer_inv` (L1-only, no
// sc1, no memory traffic). NO wbl2, NO L2 inv, NO HBM round-trip per round.
// Working set shrunk 19 -> 11 buffers (2.75 MB < 4 MB L2) via lifetime
// aliasing so the whole data plane stays L2-resident.
//
// Placement is now load-bearing for CORRECTNESS (plain stores are only
// visible through the home XCD's L2): if XCC_ID/election misbehaves, the test
// fails visibly (barrier itself cannot hang - MALL-scope counters).
//
// Spectral bounds (provable): lambda(f) in [1, ~5.2] => lambda(M) in [1, 5.5],
// lambda(S) in [1/5.75, 5.75]. Approximation intervals with margin:
//   x^{-1/2} on [0.95, 5.75], deg 11 (s=4, m=2)  -> err ~3e-5
//   x^{t}    on [0.17, 5.90], deg 39 (s=8, m=4)  -> err ~1e-6
//
// Perf history: R5 64blk+agent fences 41.1ms -> R6 16blk 102.5ms (fence HBM
// round-trip) -> R7 MALL plane 51ms -> R8c single-XCD sc0 72ms (sc0 also
// bypasses L2; placement untested) -> R9 this (predict 14-22ms).

#define NPART 32
#define AM 0.95f
#define BM 5.75f
#define AS_ 0.17f
#define BS_ 5.90f

typedef __attribute__((ext_vector_type(8))) short bf16x8;
typedef __attribute__((ext_vector_type(4))) float f32x4;

// 11 physical slots; later lifetimes alias earlier ones (verified disjoint).
enum { iXM = 0, iSQ, iFK, iU2, iU4, iCBA, iCBB, iISQ, iG, iXS, iSBA, NBUF };
#define iV2  iU2
#define iV4  iU4
#define iV3  iCBA
#define iHH  iCBA
#define iV8  iCBB
#define iSBB iISQ
#define iSBC iG
#define iPP  iXS

// Matrices stored as bf16 hi+lo planes (value = hi + lo, ~2^-16 rel err).
// PLAIN accesses: L1-cached (write-through), L2-resident (2.75 MB total).
__device__ __align__(16) short gHi[NBUF][65536];
__device__ __align__(16) short gLo[NBUF][65536];
__device__ float g_aS[256][40];   // per-step regrouped Cheb coeffs of x^{t_k}
__device__ float g_aM[12];        // regrouped Cheb coeffs of x^{-1/2}

struct __align__(128) Ctr { int v; int pad[31]; };  // one 128B line per counter
__device__ Ctr g_c1;              // barrier arrival counter (monotonic)
__device__ Ctr g_genc;            // published generation
__device__ Ctr g_slot;            // participant slot allocator
__device__ int g_xcd;             // CAS-elected home XCD (-1 = unset)

__device__ __forceinline__ short f2bf(float x) {
  unsigned u = __builtin_bit_cast(unsigned, x);
  unsigned r = (u + 0x7FFFu + ((u >> 16) & 1u)) >> 16;   // RNE to bf16
  return (short)(unsigned short)r;
}
__device__ __forceinline__ float bf2f(short h) {
  unsigned u = ((unsigned)(unsigned short)h) << 16;
  return __builtin_bit_cast(float, u);
}
__device__ __forceinline__ void wrm(int m, int idx, float v) {
  short h = f2bf(v);
  gHi[m][idx] = h;                       // plain write-through store
  gLo[m][idx] = f2bf(v - bf2f(h));
}

// C(arow, bcol) fragment of A*B; B symmetric -> read B by rows (dwordx4).
// Split hi/lo bf16: 3 MFMAs per K-chunk, ~1e-5 rel err per matmul.
// Plain loads: L1/L2 served, compiler-scheduled (fine-grained lgkmcnt/vmcnt).
__device__ __forceinline__ f32x4 mmbf(int Ai, int Bi, int arow, int bcol, int kq) {
  f32x4 acc = {0.0f, 0.0f, 0.0f, 0.0f};
  const short* ah = gHi[Ai] + arow * 256 + kq;
  const short* al = gLo[Ai] + arow * 256 + kq;
  const short* bh = gHi[Bi] + bcol * 256 + kq;
  const short* bl = gLo[Bi] + bcol * 256 + kq;
#pragma unroll
  for (int k0 = 0; k0 < 256; k0 += 32) {
    bf16x8 Ah = *(const bf16x8*)(ah + k0);
    bf16x8 Al = *(const bf16x8*)(al + k0);
    bf16x8 Bh = *(const bf16x8*)(bh + k0);
    bf16x8 Bl = *(const bf16x8*)(bl + k0);
    acc = __builtin_amdgcn_mfma_f32_16x16x32_bf16(Ah, Bh, acc, 0, 0, 0);
    acc = __builtin_amdgcn_mfma_f32_16x16x32_bf16(Al, Bh, acc, 0, 0, 0);
    acc = __builtin_amdgcn_mfma_f32_16x16x32_bf16(Ah, Bl, acc, 0, 0, 0);
  }
  return acc;
}

// Grid barrier, home-XCD edition.
// Release: each wave drains its own write-through stores (vmcnt 0) before the
// block barrier -> all block data is in the shared home-XCD L2 before the
// arrival RMW. Arrival/publish/spin: AGENT-scope (MALL) atomics -> correct and
// hang-free regardless of placement. Acquire: bare buffer_inv = invalidate
// this CU's L1 only (no sc1 -> L2 untouched, zero memory traffic); next
// round's plain loads then see the L2 truth.
__device__ __forceinline__ void gridbar(int* sgen) {
  asm volatile("s_waitcnt vmcnt(0) lgkmcnt(0)" ::: "memory");
  __syncthreads();
  if (threadIdx.x == 0) {
    int n = *sgen;
    int v = __hip_atomic_fetch_add(&g_c1.v, 1, __ATOMIC_RELAXED,
                                   __HIP_MEMORY_SCOPE_AGENT);
    if (v == NPART * n + (NPART - 1))
      __hip_atomic_store(&g_genc.v, n + 1, __ATOMIC_RELAXED,
                         __HIP_MEMORY_SCOPE_AGENT);
    while (__hip_atomic_load(&g_genc.v, __ATOMIC_RELAXED,
                             __HIP_MEMORY_SCOPE_AGENT) <= n)
      __builtin_amdgcn_s_sleep(1);
    *sgen = n + 1;
  }
  __syncthreads();
  asm volatile("buffer_inv" ::: "memory");   // L1-only; home L2 holds truth
  __builtin_amdgcn_sched_barrier(0);
}

// Chebyshev-PS regrouping: p = sum_j c_j T_j  ->  sum_i q_i(x) T_i(T_s(x)),
// q_i = sum_r a[i][r] T_r.  a[i][r] = 2c[is+r] - a[i+1][s-r] (a[i][0]=c[is]);
// a[0][r] = c[r] - 0.5 a[1][s-r]; a[0][0] = c[0].
__device__ void regroup_d(const double* c, float* outp, int s, int m) {
  double al[64];
  for (int i = m; i >= 1; i--)
    for (int r = 0; r < s; r++) {
      double v;
      if (r == 0) v = c[s * i];
      else v = 2.0 * c[s * i + r] - ((i == m) ? 0.0 : al[s * (i + 1) + (s - r)]);
      al[s * i + r] = v;
    }
  al[0] = c[0];
  for (int r = 1; r < s; r++) al[r] = c[r] - 0.5 * al[s + (s - r)];
  int tot = s * (m + 1);
  for (int j = 0; j < tot; j++) outp[j] = (float)al[j];
}

// Setup: per-step Chebyshev coefficients (128-node DCT in fp64) + state reset.
__global__ void setup_kernel(const float* __restrict__ wts) {
  const int k = blockIdx.x;
  const int lane = threadIdx.x;
  __shared__ double s_fv[128];
  __shared__ double s_c[64];
  const double PI = 3.14159265358979323846;
  if (k < 256) {
    double w0 = (double)wts[2 * k], w1 = (double)wts[2 * k + 1];
    double t = 1.0 / (1.0 + exp(w0 - w1));     // softmax(...)[:,1]
    double c0 = 0.5 * ((double)AS_ + (double)BS_), h0 = 0.5 * ((double)BS_ - (double)AS_);
    for (int i = lane; i < 128; i += 64) {
      double th = (i + 0.5) * PI / 128.0;
      double y = c0 + h0 * cos(th);
      s_fv[i] = pow(y, t);
    }
    __syncthreads();
    if (lane < 40) {
      double s = 0.0;
      for (int i = 0; i < 128; i++) {
        double th = (i + 0.5) * PI / 128.0;
        s += s_fv[i] * cos((double)lane * th);
      }
      s_c[lane] = s * ((lane == 0) ? 1.0 : 2.0) / 128.0;
    }
    __syncthreads();
    if (lane == 0) regroup_d(s_c, g_aS[k], 8, 4);
  } else {
    double c0 = 0.5 * ((double)AM + (double)BM), h0 = 0.5 * ((double)BM - (double)AM);
    for (int i = lane; i < 128; i += 64) {
      double th = (i + 0.5) * PI / 128.0;
      double y = c0 + h0 * cos(th);
      s_fv[i] = 1.0 / sqrt(y);
    }
    __syncthreads();
    if (lane < 12) {
      double s = 0.0;
      for (int i = 0; i < 128; i++) {
        double th = (i + 0.5) * PI / 128.0;
        s += s_fv[i] * cos((double)lane * th);
      }
      s_c[lane] = s * ((lane == 0) ? 1.0 : 2.0) / 128.0;
    }
    __syncthreads();
    if (lane == 0) {
      regroup_d(s_c, g_aM, 4, 2);
      g_c1.v = 0; g_genc.v = 0; g_slot.v = 0; g_xcd = -1;
    }
  }
}

// 32 participants x 512 thr, 1 block/CU (launch_bounds min 1 wg) -> the 32
// participants spread across the home XCD's 32 CUs. 256 waves = one 16x16
// C-tile per wave.
__global__ void __launch_bounds__(512, 1) frechet_kernel(const float* __restrict__ f,
                                                         float* __restrict__ out) {
  __shared__ int s_vbid;
  __shared__ int s_gen;
  int xcc;
  asm volatile("s_getreg_b32 %0, hwreg(HW_REG_XCC_ID)" : "=s"(xcc));
  xcc &= 7;
  if (threadIdx.x == 0) {
    // Elect the home XCD: first block's XCC wins (no hard-coded ID).
    int expected = -1;
    bool won = __hip_atomic_compare_exchange_strong(
        &g_xcd, &expected, xcc, __ATOMIC_RELAXED, __ATOMIC_RELAXED,
        __HIP_MEMORY_SCOPE_AGENT);
    int chosen = won ? xcc : expected;
    int slot = -1;
    if (chosen == xcc)
      slot = __hip_atomic_fetch_add(&g_slot.v, 1, __ATOMIC_RELAXED,
                                    __HIP_MEMORY_SCOPE_AGENT);
    s_vbid = slot;
    s_gen = 0;
  }
  __syncthreads();
  const int vbid = s_vbid;
  if (vbid < 0 || vbid >= NPART) return;   // off-home or overflow: exit

  const int tid = threadIdx.x;
  const int lane = tid & 63, wave = tid >> 6;
  const int tr = (vbid >> 2) * 32, tc = (vbid & 3) * 64;  // 8x4 grid of 32x64
  const int sr = (wave >> 2) * 16, sc = (wave & 3) * 16;  // 2x4 waves of 16x16
  const int arow = tr + sr + (lane & 15);     // A-fragment row (global)
  const int colg = tc + sc + (lane & 15);     // C col = B-sym row (global)
  const int kq = (lane >> 4) * 8;             // K sub-offset within chunk
  const int row0 = tr + sr + (lane >> 4) * 4; // C rows for acc[0..3]
  const int fbase = (vbid * 512 + tid) * 4;   // 4 contiguous f elems / thread

  const float sM = 2.0f / (BM - AM), cM = 0.5f * (AM + BM);
  const float sS = 2.0f / (BS_ - AS_), cS = 0.5f * (AS_ + BS_);

  // Register-carried per-thread values (each at idx=(row0+r)*256+colg; every
  // scalar operand below was produced by THIS thread in an earlier round).
  float xmr[4], u2r[4], cbar[4], qm1r[4], qm0r[4], isqr[4];
  float xsr[4], v2r[4], v3r[4], v4r[4];
  float qs3r[4], qs2r[4], qs1r[4], qs0r[4], sbar[4], sbbr[4], sbcr[4];

  // Init: XM = sM*(I - cM*I) at tile positions; stage f_0 into bf16 planes.
  {
    float4 f0 = *(const float4*)(f + fbase);
    float fv[4] = {f0.x, f0.y, f0.z, f0.w};
#pragma unroll
    for (int r = 0; r < 4; r++) {
      int row = row0 + r, idx = row * 256 + colg;
      xmr[r] = (row == colg) ? sM * (1.0f - cM) : 0.0f;
      wrm(iXM, idx, xmr[r]);
      wrm(iFK, fbase + r, fv[r]);
    }
  }
  gridbar(&s_gen);

  for (int k = 0; k < 256; k++) {
    const float* aS = g_aS[k];
    const float* aM = g_aM;

    // ---- ISQ = p(M) ~ M^{-1/2}: s=4, m=2, deg 11 ----
    { // r1: U2 = 2*XM*XM - I
      f32x4 a = mmbf(iXM, iXM, arow, colg, kq);
#pragma unroll
      for (int r = 0; r < 4; r++) {
        int row = row0 + r, idx = row * 256 + colg;
        u2r[r] = 2.0f * a[r] - ((row == colg) ? 1.0f : 0.0f);
        wrm(iU2, idx, u2r[r]);
      }
    }
    gridbar(&s_gen);
    { // r2: U3 (regs), U4 ; q2 (CBA) global, Q1/Q0 combos register-only
      f32x4 a3 = mmbf(iXM, iU2, arow, colg, kq);
      f32x4 a4 = mmbf(iU2, iU2, arow, colg, kq);
#pragma unroll
      for (int r = 0; r < 4; r++) {
        int row = row0 + r, idx = row * 256 + colg;
        float dI = (row == colg) ? 1.0f : 0.0f;
        float xm = xmr[r], u2 = u2r[r];
        float u3 = 2.0f * a3[r] - xm;
        wrm(iU4, idx, 2.0f * a4[r] - dI);
        cbar[r] = aM[8] * dI + aM[9] * xm + aM[10] * u2 + aM[11] * u3;
        wrm(iCBA, idx, cbar[r]);
        qm1r[r] = aM[4] * dI + aM[5] * xm + aM[6] * u2 + aM[7] * u3;
        qm0r[r] = aM[0] * dI + aM[1] * xm + aM[2] * u2 + aM[3] * u3;
      }
    }
    gridbar(&s_gen);
    { // r3: CBB = 2*U4*CBA + Q1
      f32x4 a = mmbf(iU4, iCBA, arow, colg, kq);
#pragma unroll
      for (int r = 0; r < 4; r++) {
        int idx = (row0 + r) * 256 + colg;
        wrm(iCBB, idx, 2.0f * a[r] + qm1r[r]);
      }
    }
    gridbar(&s_gen);
    { // r4: ISQ = U4*CBB - CBA + Q0
      f32x4 a = mmbf(iU4, iCBB, arow, colg, kq);
#pragma unroll
      for (int r = 0; r < 4; r++) {
        int idx = (row0 + r) * 256 + colg;
        isqr[r] = a[r] - cbar[r] + qm0r[r];
        wrm(iISQ, idx, isqr[r]);
      }
    }
    gridbar(&s_gen);
    { // r5: SQ = (1/sM)*XM*ISQ + cM*ISQ ; G = ISQ*FK
      f32x4 a = mmbf(iXM, iISQ, arow, colg, kq);
      f32x4 b = mmbf(iISQ, iFK, arow, colg, kq);
#pragma unroll
      for (int r = 0; r < 4; r++) {
        int idx = (row0 + r) * 256 + colg;
        wrm(iSQ, idx, a[r] * (1.0f / sM) + cM * isqr[r]);
        wrm(iG, idx, b[r]);
      }
    }
    gridbar(&s_gen);
    { // r6: XS = sS*(G*ISQ) - sS*cS*I
      f32x4 a = mmbf(iG, iISQ, arow, colg, kq);
#pragma unroll
      for (int r = 0; r < 4; r++) {
        int row = row0 + r, idx = row * 256 + colg;
        xsr[r] = sS * a[r] - sS * cS * ((row == colg) ? 1.0f : 0.0f);
        wrm(iXS, idx, xsr[r]);
      }
    }
    gridbar(&s_gen);

    // ---- P = p(S) ~ S^t: s=8, m=4, deg 39 ----
    { // r7: V2 = 2*XS*XS - I   (V2 aliases U2's slot; U2 dead after r2)
      f32x4 a = mmbf(iXS, iXS, arow, colg, kq);
#pragma unroll
      for (int r = 0; r < 4; r++) {
        int row = row0 + r, idx = row * 256 + colg;
        v2r[r] = 2.0f * a[r] - ((row == colg) ? 1.0f : 0.0f);
        wrm(iV2, idx, v2r[r]);
      }
    }
    gridbar(&s_gen);
    { // r8: V3 = 2*XS*V2 - XS ; V4 = 2*V2*V2 - I  (alias CBA / U4 slots)
      f32x4 a = mmbf(iXS, iV2, arow, colg, kq);
      f32x4 b = mmbf(iV2, iV2, arow, colg, kq);
#pragma unroll
      for (int r = 0; r < 4; r++) {
        int row = row0 + r, idx = row * 256 + colg;
        float dI = (row == colg) ? 1.0f : 0.0f;
        v3r[r] = 2.0f * a[r] - xsr[r];
        v4r[r] = 2.0f * b[r] - dI;
        wrm(iV3, idx, v3r[r]);
        wrm(iV4, idx, v4r[r]);
      }
    }
    gridbar(&s_gen);
    { // r9: V5..V7 (regs), V8 (alias CBB), q4->SBA; Q3..Q0 regs; f_{k+1}
      f32x4 fq;
      if (k < 255) {
        const f32x4* fp = (const f32x4*)(f + (size_t)(k + 1) * 65536 + fbase);
        fq = __builtin_nontemporal_load(fp);   // don't pollute home-XCD L2
      } else {
        fq = (f32x4){0.f, 0.f, 0.f, 0.f};
      }
      f32x4 a5 = mmbf(iV2, iV3, arow, colg, kq);
      f32x4 a6 = mmbf(iV3, iV3, arow, colg, kq);
      f32x4 a7 = mmbf(iV3, iV4, arow, colg, kq);
      f32x4 a8 = mmbf(iV4, iV4, arow, colg, kq);
#pragma unroll
      for (int r = 0; r < 4; r++) {
        int row = row0 + r, idx = row * 256 + colg;
        float dI = (row == colg) ? 1.0f : 0.0f;
        float xs = xsr[r], v2 = v2r[r], v3 = v3r[r], v4 = v4r[r];
        float v5 = 2.0f * a5[r] - xs;   // T5 = 2*T2*T3 - T1
        float v6 = 2.0f * a6[r] - dI;   // T6 = 2*T3*T3 - T0
        float v7 = 2.0f * a7[r] - xs;   // T7 = 2*T3*T4 - T1
        float v8 = 2.0f * a8[r] - dI;   // T8 = 2*T4*T4 - T0
        wrm(iV8, idx, v8);
        sbar[r] = aS[32] * dI + aS[33] * xs + aS[34] * v2 + aS[35] * v3 +
                  aS[36] * v4 + aS[37] * v5 + aS[38] * v6 + aS[39] * v7;
        wrm(iSBA, idx, sbar[r]);
        qs3r[r] = aS[24] * dI + aS[25] * xs + aS[26] * v2 + aS[27] * v3 +
                  aS[28] * v4 + aS[29] * v5 + aS[30] * v6 + aS[31] * v7;
        qs2r[r] = aS[16] * dI + aS[17] * xs + aS[18] * v2 + aS[19] * v3 +
                  aS[20] * v4 + aS[21] * v5 + aS[22] * v6 + aS[23] * v7;
        qs1r[r] = aS[8] * dI + aS[9] * xs + aS[10] * v2 + aS[11] * v3 +
                  aS[12] * v4 + aS[13] * v5 + aS[14] * v6 + aS[15] * v7;
        qs0r[r] = aS[0] * dI + aS[1] * xs + aS[2] * v2 + aS[3] * v3 +
                  aS[4] * v4 + aS[5] * v5 + aS[6] * v6 + aS[7] * v7;
      }
      if (k < 255) {
        float fv[4] = {fq[0], fq[1], fq[2], fq[3]};
#pragma unroll
        for (int r = 0; r < 4; r++) wrm(iFK, fbase + r, fv[r]);
      }
    }
    gridbar(&s_gen);
    { // r10: b3 = 2*V8*b4 + Q3   (SBB aliases ISQ slot; ISQ dead after r6)
      f32x4 a = mmbf(iV8, iSBA, arow, colg, kq);
#pragma unroll
      for (int r = 0; r < 4; r++) {
        int idx = (row0 + r) * 256 + colg;
        sbbr[r] = 2.0f * a[r] + qs3r[r];
        wrm(iSBB, idx, sbbr[r]);
      }
    }
    gridbar(&s_gen);
    { // r11: b2 = 2*V8*b3 - b4 + Q2   (SBC aliases G slot; G dead after r6)
      f32x4 a = mmbf(iV8, iSBB, arow, colg, kq);
#pragma unroll
      for (int r = 0; r < 4; r++) {
        int idx = (row0 + r) * 256 + colg;
        sbcr[r] = 2.0f * a[r] - sbar[r] + qs2r[r];
        wrm(iSBC, idx, sbcr[r]);
      }
    }
    gridbar(&s_gen);
    { // r12: b1 = 2*V8*b2 - b3 + Q1  (rewrites SBA slot; b4 dead after r11)
      f32x4 a = mmbf(iV8, iSBC, arow, colg, kq);
#pragma unroll
      for (int r = 0; r < 4; r++) {
        int idx = (row0 + r) * 256 + colg;
        wrm(iSBA, idx, 2.0f * a[r] - sbbr[r] + qs1r[r]);
      }
    }
    gridbar(&s_gen);
    { // r13: P = V8*b1 - b2 + Q0   (PP aliases XS slot; XS dead after r8)
      f32x4 a = mmbf(iV8, iSBA, arow, colg, kq);
#pragma unroll
      for (int r = 0; r < 4; r++) {
        int idx = (row0 + r) * 256 + colg;
        wrm(iPP, idx, a[r] - sbcr[r] + qs0r[r]);
      }
    }
    gridbar(&s_gen);
    { // r14: HH = SQ*P   (HH aliases V3/CBA slot; V3 dead after r9)
      f32x4 a = mmbf(iSQ, iPP, arow, colg, kq);
#pragma unroll
      for (int r = 0; r < 4; r++) {
        int idx = (row0 + r) * 256 + colg;
        wrm(iHH, idx, a[r]);
      }
    }
    gridbar(&s_gen);
    { // r15: Mn = HH*SQ -> out[k] (fp32, NT); XM_next = sM*(Mn - cM*I)
      f32x4 a = mmbf(iHH, iSQ, arow, colg, kq);
      float* ok = out + (size_t)k * 65536;
#pragma unroll
      for (int r = 0; r < 4; r++) {
        int row = row0 + r, idx = row * 256 + colg;
        float dI = (row == colg) ? 1.0f : 0.0f;
        float v = a[r];
        __builtin_nontemporal_store(v, ok + idx);
        xmr[r] = sM * (v - cM * dI);
        wrm(iXM, idx, xmr[r]);
      }
    }
    gridbar(&s_gen);
  }
}

extern "C" void kernel_launch(void* const* d_in, const int* in_sizes, int n_in,
                              void* d_out, int out_size, void* d_ws, size_t ws_size,
                              hipStream_t stream) {
  (void)in_sizes; (void)n_in; (void)d_ws; (void)ws_size; (void)out_size;
  const float* f = (const float*)d_in[0];
  const float* w = (const float*)d_in[1];
  float* out = (float*)d_out;

  setup_kernel<<<dim3(257), dim3(64), 0, stream>>>(w);

  // 1024 probe blocks; the first block CAS-elects its XCD as "home"; the
  // first NPART=32 blocks landing on the home XCD participate (1 block/CU ->
  // spread over its 32 CUs); all others exit instantly. The barrier uses
  // MALL-scope atomics, so a broken placement produces wrong data (visible),
  // never a hang.
  frechet_kernel<<<dim3(1024), dim3(512), 0, stream>>>(f, out);
}